// Round 4
// baseline (1323.767 us; speedup 1.0000x reference)
//
#include <hip/hip_runtime.h>

// VectorQuantizer: x (4,256,16,32,32) f32, weight (1024,256) f32.
// out[n*256+c] = weight[argmin_k d_np(n,k)][c], n in BTHW token order.
//
// R3 (passed, absmax 0) established the contract: replicate numpy fp32
// bit-for-bit (pairwise sumsq; sgemm = sequential fma chain ascending c;
// d = fl(fl(sx+sw) - 2m); argmin first-index).
//
// R4: bf16-MFMA screen + exact-np resolve of near-ties.
//   screen t(n,k) = sw_np[k] - 2*(xh.wh + xh.wl + xl.wh)   [3 MFMA products]
//   |(d_np - sx) - t| <= ~7e-5  (np rounding 3.2e-5 + split/accum ~2.5e-5)
//   gap > MARGIN=4e-4 -> screen argmin == np argmin (provable).
//   gap <= MARGIN (~6% tokens) -> full np-exact rescore (R3 semantics).

typedef __attribute__((ext_vector_type(8))) short bf16x8;
typedef __attribute__((ext_vector_type(4))) float f32x4;

#define MARGIN 4e-4f

__device__ __forceinline__ unsigned short bf16_rne(float f) {
    unsigned int u = __float_as_uint(f);
    unsigned int r = u + 0x7fffu + ((u >> 16) & 1u);
    return (unsigned short)(r >> 16);
}
__device__ __forceinline__ float bf16_to_f(unsigned short h) {
    return __uint_as_float(((unsigned int)h) << 16);
}

// ---- numpy pairwise sum of squares, n=256, contract OFF ----
__device__ __forceinline__ float np_sumsq_256(const float* __restrict__ p,
                                              long stride) {
#pragma clang fp contract(off)
    float half[2];
    #pragma unroll
    for (int h = 0; h < 2; ++h) {
        const float* q = p + (long)h * 128 * stride;
        float r[8];
        #pragma unroll
        for (int j = 0; j < 8; ++j) { float v = q[(long)j * stride]; r[j] = v * v; }
        for (int i = 8; i < 128; i += 8) {
            #pragma unroll
            for (int j = 0; j < 8; ++j) {
                float v = q[(long)(i + j) * stride];
                r[j] = r[j] + v * v;
            }
        }
        half[h] = ((r[0] + r[1]) + (r[2] + r[3])) + ((r[4] + r[5]) + (r[6] + r[7]));
    }
    return half[0] + half[1];
}

__global__ __launch_bounds__(256) void vq_sxq(const float* __restrict__ x,
                                              float* __restrict__ sxq) {
    const int n = blockIdx.x * 256 + threadIdx.x;
    const int b = n >> 14, thw = n & 16383;
    sxq[n] = np_sumsq_256(x + (long)b * 4194304 + thw, 16384);
}

__global__ __launch_bounds__(256) void vq_swq(const float* __restrict__ w,
                                              float* __restrict__ swq) {
    const int k = blockIdx.x * 256 + threadIdx.x;
    swq[k] = np_sumsq_256(w + (long)k * 256, 1);
}

// ---- split weight into bf16 hi/lo planes (same layout) ----
__global__ __launch_bounds__(256) void vq_split_w(const float* __restrict__ w,
                                                  unsigned short* __restrict__ wh,
                                                  unsigned short* __restrict__ wl) {
    const int i = blockIdx.x * 256 + threadIdx.x;   // 262144
    const float v = w[i];
    const unsigned short h = bf16_rne(v);
    wh[i] = h;
    wl[i] = bf16_rne(v - bf16_to_f(h));
}

// ---- split + transpose x into bf16 planes xh[n][c], xl[n][c] ----
// block = (b, 64-c tile, 64-thw tile); LDS transpose, pad 65 (bank-safe).
__global__ __launch_bounds__(256) void vq_split_x(const float* __restrict__ x,
                                                  unsigned short* __restrict__ xh,
                                                  unsigned short* __restrict__ xl) {
    __shared__ float tile[64][65];
    const int bid = blockIdx.x;
    const int b  = bid >> 10;
    const int ct = (bid >> 8) & 3;
    const int tt = bid & 255;
    const float* xb = x + (size_t)b * 4194304 + (size_t)(ct * 64) * 16384 + tt * 64;
    const int tw = threadIdx.x & 63;
    const int cg = threadIdx.x >> 6;   // 0..3
    #pragma unroll
    for (int i = 0; i < 16; i++) {
        const int cc = cg * 16 + i;
        tile[cc][tw] = xb[(size_t)cc * 16384 + tw];   // coalesced over tw
    }
    __syncthreads();
    const int c = threadIdx.x & 63;
    #pragma unroll
    for (int i = 0; i < 16; i++) {
        const int t = cg * 16 + i;
        const float v = tile[c][t];
        const unsigned short h = bf16_rne(v);
        const unsigned short l = bf16_rne(v - bf16_to_f(h));
        const size_t n = (size_t)b * 16384 + tt * 64 + t;
        xh[n * 256 + ct * 64 + c] = h;   // coalesced over c
        xl[n * 256 + ct * 64 + c] = l;
    }
}

// ---- screen: 3-product bf16 MFMA scores, per-token top-2, flag near-ties ----
// block: 64 tokens; wave wv covers codes [256wv, 256wv+256).
__global__ __launch_bounds__(256) void vq_screen(const unsigned short* __restrict__ xh,
                                                 const unsigned short* __restrict__ xl,
                                                 const unsigned short* __restrict__ wh,
                                                 const unsigned short* __restrict__ wl,
                                                 const float* __restrict__ swq,
                                                 int* __restrict__ winner,
                                                 int* __restrict__ flag,
                                                 int* __restrict__ count) {
    __shared__ float sw_s[1024];
    __shared__ float r_m1[4][64];
    __shared__ float r_m2[4][64];
    __shared__ int   r_i1[4][64];
    const int tid = threadIdx.x;
    for (int i = tid; i < 1024; i += 256) sw_s[i] = swq[i];
    __syncthreads();

    const int n0 = blockIdx.x * 64;
    const int wv = tid >> 6, lane = tid & 63;
    const int l15 = lane & 15, lq = lane >> 4;

    // a-frag: A[m=l15][k=lq*8+j] = xplane[token n0+16mt+l15][32cs + lq*8+j]
    // b-frag: B[k=lq*8+j][n=l15] = wplane[code 256wv+16kt+l15][32cs + lq*8+j]
    const size_t aoff = ((size_t)n0 + l15) * 256 + lq * 8;
    const size_t boff = ((size_t)(wv * 256) + l15) * 256 + lq * 8;

    float m1[16], m2[16];
    int   i1[16];
    #pragma unroll
    for (int r = 0; r < 16; r++) { m1[r] = 1e30f; m2[r] = 1e30f; i1[r] = 0; }

    for (int kt = 0; kt < 16; kt++) {
        f32x4 acc[4];
        #pragma unroll
        for (int mt = 0; mt < 4; mt++) acc[mt] = (f32x4){0.f, 0.f, 0.f, 0.f};
        #pragma unroll
        for (int cs = 0; cs < 8; cs++) {
            const bf16x8 bh = *(const bf16x8*)(wh + boff + (size_t)kt * 4096 + cs * 32);
            const bf16x8 bl = *(const bf16x8*)(wl + boff + (size_t)kt * 4096 + cs * 32);
            #pragma unroll
            for (int mt = 0; mt < 4; mt++) {
                const bf16x8 ah = *(const bf16x8*)(xh + aoff + (size_t)mt * 4096 + cs * 32);
                const bf16x8 al = *(const bf16x8*)(xl + aoff + (size_t)mt * 4096 + cs * 32);
                acc[mt] = __builtin_amdgcn_mfma_f32_16x16x32_bf16(ah, bh, acc[mt], 0, 0, 0);
                acc[mt] = __builtin_amdgcn_mfma_f32_16x16x32_bf16(al, bh, acc[mt], 0, 0, 0);
                acc[mt] = __builtin_amdgcn_mfma_f32_16x16x32_bf16(ah, bl, acc[mt], 0, 0, 0);
            }
        }
        const int k = wv * 256 + kt * 16 + l15;   // C/D col = l15
        const float snk = sw_s[k];
        #pragma unroll
        for (int mt = 0; mt < 4; mt++)
            #pragma unroll
            for (int r = 0; r < 4; r++) {
                const float t = fmaf(-2.f, acc[mt][r], snk);
                const int row = mt * 4 + r;       // token = n0+16mt+4lq+r
                if (t < m1[row]) { m2[row] = m1[row]; m1[row] = t; i1[row] = k; }
                else              m2[row] = fminf(m2[row], t);
            }
    }

    // merge top-2 across the 16 lanes sharing lq (codes interleave, tokens same)
    #pragma unroll
    for (int mm = 1; mm < 16; mm <<= 1) {
        #pragma unroll
        for (int row = 0; row < 16; row++) {
            const float om1 = __shfl_xor(m1[row], mm);
            const int   oi1 = __shfl_xor(i1[row], mm);
            const float om2 = __shfl_xor(m2[row], mm);
            if (om1 < m1[row]) { m2[row] = fminf(m1[row], om2); m1[row] = om1; i1[row] = oi1; }
            else               { m2[row] = fminf(m2[row], om1); }
        }
    }
    if (l15 == 0) {
        #pragma unroll
        for (int mt = 0; mt < 4; mt++)
            #pragma unroll
            for (int r = 0; r < 4; r++) {
                const int tok = mt * 16 + lq * 4 + r;
                r_m1[wv][tok] = m1[mt * 4 + r];
                r_m2[wv][tok] = m2[mt * 4 + r];
                r_i1[wv][tok] = i1[mt * 4 + r];
            }
    }
    __syncthreads();
    if (tid < 64) {
        float b1 = r_m1[0][tid], b2 = r_m2[0][tid];
        int   bi = r_i1[0][tid];
        #pragma unroll
        for (int w2 = 1; w2 < 4; w2++) {
            const float o1 = r_m1[w2][tid], o2 = r_m2[w2][tid];
            const int   oi = r_i1[w2][tid];
            if (o1 < b1) { b2 = fminf(b1, o2); b1 = o1; bi = oi; }
            else           b2 = fminf(b2, o1);
        }
        const int n = n0 + tid;
        if (b2 - b1 > MARGIN) {
            winner[n] = bi;                      // unique np-argmin, proven
        } else {
            winner[n] = -1;
            const int p = atomicAdd(count, 1);
            flag[p] = n;
        }
    }
}

// ---- resolve flagged tokens with the exact R3 numpy semantics ----
// block: 16 tokens/iter, grid-stride; thread (ts=tid>>4, kg=tid&15) covers
// codes k = kg + 16j (j=0..63), 4 interleaved sequential fma chains.
__global__ __launch_bounds__(256) void vq_resolve(const float* __restrict__ x,
                                                  const float* __restrict__ w,
                                                  const float* __restrict__ sxq,
                                                  const float* __restrict__ swq,
                                                  const int* __restrict__ flag,
                                                  const int* __restrict__ count,
                                                  int* __restrict__ winner) {
    __shared__ float xsh[16][257];
    __shared__ int   toks[16];
    const int cnt = *count;
    const int tid = threadIdx.x;
    const int ts = tid >> 4;
    const int kg = tid & 15;

    for (int base = blockIdx.x * 16; base < cnt; base += gridDim.x * 16) {
        if (tid < 16) toks[tid] = (base + tid < cnt) ? flag[base + tid] : -1;
        __syncthreads();
        #pragma unroll 1
        for (int i = 0; i < 16; i++) {
            const int n = toks[i];
            float v = 0.f;
            if (n >= 0) {
                const int b = n >> 14, thw = n & 16383;
                v = x[(size_t)b * 4194304 + (size_t)tid * 16384 + thw];
            }
            xsh[i][tid] = v;
        }
        __syncthreads();

        const int n = toks[ts];
        float bd = 1e30f;
        int   bk = 0x7fffffff;
        if (n >= 0) {
            const float sx = sxq[n];
            for (int j0 = 0; j0 < 64; j0 += 4) {
                const int k0 = kg + (j0 + 0) * 16;
                const int k1 = kg + (j0 + 1) * 16;
                const int k2 = kg + (j0 + 2) * 16;
                const int k3 = kg + (j0 + 3) * 16;
                const float* w0 = w + (size_t)k0 * 256;
                const float* w1 = w + (size_t)k1 * 256;
                const float* w2 = w + (size_t)k2 * 256;
                const float* w3 = w + (size_t)k3 * 256;
                float a0 = 0.f, a1 = 0.f, a2 = 0.f, a3 = 0.f;
                for (int c = 0; c < 256; c++) {   // np sgemm: ascending fma chain
                    const float xc = xsh[ts][c];
                    a0 = fmaf(xc, w0[c], a0);
                    a1 = fmaf(xc, w1[c], a1);
                    a2 = fmaf(xc, w2[c], a2);
                    a3 = fmaf(xc, w3[c], a3);
                }
                float s, d;
                s = sx + swq[k0]; d = fmaf(-2.f, a0, s); if (d < bd) { bd = d; bk = k0; }
                s = sx + swq[k1]; d = fmaf(-2.f, a1, s); if (d < bd) { bd = d; bk = k1; }
                s = sx + swq[k2]; d = fmaf(-2.f, a2, s); if (d < bd) { bd = d; bk = k2; }
                s = sx + swq[k3]; d = fmaf(-2.f, a3, s); if (d < bd) { bd = d; bk = k3; }
            }
        }
        // lexicographic (d, k) merge across the 16 kg lanes (contiguous in wave)
        #pragma unroll
        for (int mm = 1; mm < 16; mm <<= 1) {
            const float od = __shfl_xor(bd, mm);
            const int   ok = __shfl_xor(bk, mm);
            if (od < bd || (od == bd && ok < bk)) { bd = od; bk = ok; }
        }
        if (n >= 0 && kg == 0) winner[n] = bk;
        __syncthreads();
    }
}

// ---- gather ----
__global__ __launch_bounds__(256) void vq_gather(const float* __restrict__ w,
                                                 const int* __restrict__ winner,
                                                 float* __restrict__ out) {
    const size_t idx = (size_t)blockIdx.x * 256 + threadIdx.x;  // 65536*64 float4s
    const int n = (int)(idx >> 6);
    const int c4 = (int)(idx & 63);
    reinterpret_cast<float4*>(out)[idx] =
        reinterpret_cast<const float4*>(w + (size_t)winner[n] * 256)[c4];
}

// ================= R3 fallback (proven-correct, ~967 us) =================
#define TPB 32
__global__ __launch_bounds__(64) void vq_wt(const float* __restrict__ w,
                                            float* __restrict__ wt) {
    const int k = blockIdx.x;
    const int lane = threadIdx.x;
    const float4 v = reinterpret_cast<const float4*>(w + (size_t)k * 256)[lane];
    wt[(size_t)(4 * lane + 0) * 1024 + k] = v.x;
    wt[(size_t)(4 * lane + 1) * 1024 + k] = v.y;
    wt[(size_t)(4 * lane + 2) * 1024 + k] = v.z;
    wt[(size_t)(4 * lane + 3) * 1024 + k] = v.w;
}

__global__ __launch_bounds__(256) void vq_main(const float* __restrict__ x,
                                               const float* __restrict__ sxq,
                                               const float* __restrict__ swq,
                                               const float* __restrict__ wt,
                                               const float* __restrict__ weight,
                                               float* __restrict__ out) {
    __shared__ __align__(16) float xs[256 * TPB];
    __shared__ float wn[1024];
    __shared__ float sxs[TPB];
    __shared__ float red_s[4][TPB];
    __shared__ int   red_i[4][TPB];
    __shared__ int   fidx[TPB];

    const int tid = threadIdx.x;
    const int n0 = blockIdx.x * TPB;
    const int b = n0 >> 14, thw = n0 & 16383;
    const float* xb = x + (size_t)b * 4194304 + thw;

    for (int i = tid; i < 256 * TPB; i += 256) {
        int t = i & (TPB - 1);
        int c = i >> 5;
        xs[c * TPB + t] = xb[(size_t)c * 16384 + t];
    }
    for (int i = tid; i < 1024; i += 256) wn[i] = swq[i];
    if (tid < TPB) sxs[tid] = sxq[n0 + tid];
    __syncthreads();

    const int lane = tid & 63, wv = tid >> 6;
    const int tg = lane & 7, cg = lane >> 3;
    float sxr[4];
    #pragma unroll
    for (int j = 0; j < 4; j++) sxr[j] = sxs[4 * tg + j];
    float bestS[4]; int bestI[4];
    #pragma unroll
    for (int j = 0; j < 4; j++) { bestS[j] = 1e30f; bestI[j] = 0x7fffffff; }

    for (int kb = 0; kb < 1024; kb += 256) {
        const int kbase = kb + 64 * wv + 8 * cg;
        float acc[4][8];
        #pragma unroll
        for (int j = 0; j < 4; j++)
            #pragma unroll
            for (int q = 0; q < 8; q++) acc[j][q] = 0.f;
        const float* wtp = wt + kbase;
        #pragma unroll 4
        for (int c = 0; c < 256; c++) {
            const float4 xv = *reinterpret_cast<const float4*>(&xs[c * TPB + 4 * tg]);
            const float4 w0 = *reinterpret_cast<const float4*>(wtp + (size_t)c * 1024);
            const float4 w1 = *reinterpret_cast<const float4*>(wtp + (size_t)c * 1024 + 4);
            const float xr[4] = {xv.x, xv.y, xv.z, xv.w};
            const float wr[8] = {w0.x, w0.y, w0.z, w0.w, w1.x, w1.y, w1.z, w1.w};
            #pragma unroll
            for (int j = 0; j < 4; j++)
                #pragma unroll
                for (int q = 0; q < 8; q++)
                    acc[j][q] = fmaf(xr[j], wr[q], acc[j][q]);
        }
        #pragma unroll
        for (int q = 0; q < 8; q++) {
            const int k = kbase + q;
            const float wnk = wn[k];
            #pragma unroll
            for (int j = 0; j < 4; j++) {
                const float s1 = sxr[j] + wnk;
                const float d = fmaf(-2.f, acc[j][q], s1);
                if (d < bestS[j]) { bestS[j] = d; bestI[j] = k; }
            }
        }
    }
    #pragma unroll
    for (int m = 8; m < 64; m <<= 1) {
        #pragma unroll
        for (int j = 0; j < 4; j++) {
            const float os = __shfl_xor(bestS[j], m);
            const int   oi = __shfl_xor(bestI[j], m);
            if (os < bestS[j] || (os == bestS[j] && oi < bestI[j])) {
                bestS[j] = os; bestI[j] = oi;
            }
        }
    }
    if (cg == 0) {
        #pragma unroll
        for (int j = 0; j < 4; j++) {
            red_s[wv][4 * tg + j] = bestS[j];
            red_i[wv][4 * tg + j] = bestI[j];
        }
    }
    __syncthreads();
    if (tid < TPB) {
        float bs = red_s[0][tid]; int bi = red_i[0][tid];
        #pragma unroll
        for (int w2 = 1; w2 < 4; w2++) {
            const float s2 = red_s[w2][tid];
            const int   i2 = red_i[w2][tid];
            if (s2 < bs || (s2 == bs && i2 < bi)) { bs = s2; bi = i2; }
        }
        fidx[tid] = bi;
    }
    __syncthreads();
    for (int i = tid; i < TPB * 256; i += 256) {
        const int t = i >> 8, c = i & 255;
        out[(size_t)(n0 + t) * 256 + c] = weight[(size_t)fidx[t] * 256 + c];
    }
}

// ================= launch =================
extern "C" void kernel_launch(void* const* d_in, const int* in_sizes, int n_in,
                              void* d_out, int out_size, void* d_ws, size_t ws_size,
                              hipStream_t stream) {
    const float* x = (const float*)d_in[0];
    const float* w = (const float*)d_in[1];
    float* out = (float*)d_out;

    // fast-path workspace layout
    char* p = (char*)d_ws;
    int*   count  = (int*)p;                         p += 256;
    int*   winner = (int*)p;                         p += 65536 * 4;
    int*   flag   = (int*)p;                         p += 65536 * 4;
    float* sxq    = (float*)p;                       p += 65536 * 4;
    float* swq    = (float*)p;                       p += 1024 * 4;
    unsigned short* wh = (unsigned short*)p;         p += 262144 * 2;
    unsigned short* wl = (unsigned short*)p;         p += 262144 * 2;
    unsigned short* xh = (unsigned short*)p;         p += 16777216 * 2;
    unsigned short* xl = (unsigned short*)p;         p += 16777216 * 2;
    const size_t need_fast = (size_t)(p - (char*)d_ws);

    if (ws_size >= need_fast) {
        hipMemsetAsync(count, 0, 4, stream);
        vq_sxq<<<256, 256, 0, stream>>>(x, sxq);
        vq_swq<<<4, 256, 0, stream>>>(w, swq);
        vq_split_w<<<1024, 256, 0, stream>>>(w, wh, wl);
        vq_split_x<<<4096, 256, 0, stream>>>(x, xh, xl);
        vq_screen<<<1024, 256, 0, stream>>>(xh, xl, wh, wl, swq, winner, flag, count);
        vq_resolve<<<256, 256, 0, stream>>>(x, w, sxq, swq, flag, count, winner);
        vq_gather<<<16384, 256, 0, stream>>>(w, winner, out);
    } else {
        // proven R3 fallback (needs ~1.3 MB)
        float* sxq2 = (float*)d_ws;
        float* swq2 = sxq2 + 65536;
        float* wt   = swq2 + 1024;
        vq_sxq<<<256, 256, 0, stream>>>(x, sxq2);
        vq_swq<<<4, 256, 0, stream>>>(w, swq2);
        vq_wt<<<1024, 64, 0, stream>>>(w, wt);
        vq_main<<<65536 / TPB, 256, 0, stream>>>(x, sxq2, swq2, wt, w, out);
    }
}

// Round 5
// 502.861 us; speedup vs baseline: 2.6325x; 2.6325x over previous
//
#include <hip/hip_runtime.h>

// VectorQuantizer: x (4,256,16,32,32) f32, weight (1024,256) f32.
// out[n*256+c] = weight[argmin_k d_np(n,k)][c], n in BTHW token order.
//
// Contract (R3, passed absmax 0): replicate numpy fp32 bit-for-bit:
//   sx/sw = np pairwise sumsq; m = sgemm sequential fma chain ascending c;
//   d = fl(fl(sx+sw) - 2m); argmin first-index.
// R4 (passed): bf16-MFMA 3-product screen (err bound ~5e-5 << MARGIN=4e-4)
//   + exact resolve of near-ties. But resolve was latency-bound (919 us:
//   scalar uncoalesced w loads serialized per c-iteration).
// R5: resolve v2 — transposed-weight coalesced loads, 16 fma chains/thread,
//   4 tokens/block-iteration, grid-stride. Screen untouched.

typedef __attribute__((ext_vector_type(8))) short bf16x8;
typedef __attribute__((ext_vector_type(4))) float f32x4;

#define MARGIN 4e-4f

__device__ __forceinline__ unsigned short bf16_rne(float f) {
    unsigned int u = __float_as_uint(f);
    unsigned int r = u + 0x7fffu + ((u >> 16) & 1u);
    return (unsigned short)(r >> 16);
}
__device__ __forceinline__ float bf16_to_f(unsigned short h) {
    return __uint_as_float(((unsigned int)h) << 16);
}

// ---- numpy pairwise sum of squares, n=256, contract OFF ----
__device__ __forceinline__ float np_sumsq_256(const float* __restrict__ p,
                                              long stride) {
#pragma clang fp contract(off)
    float half[2];
    #pragma unroll
    for (int h = 0; h < 2; ++h) {
        const float* q = p + (long)h * 128 * stride;
        float r[8];
        #pragma unroll
        for (int j = 0; j < 8; ++j) { float v = q[(long)j * stride]; r[j] = v * v; }
        for (int i = 8; i < 128; i += 8) {
            #pragma unroll
            for (int j = 0; j < 8; ++j) {
                float v = q[(long)(i + j) * stride];
                r[j] = r[j] + v * v;
            }
        }
        half[h] = ((r[0] + r[1]) + (r[2] + r[3])) + ((r[4] + r[5]) + (r[6] + r[7]));
    }
    return half[0] + half[1];
}

__global__ __launch_bounds__(256) void vq_sxq(const float* __restrict__ x,
                                              float* __restrict__ sxq) {
    const int n = blockIdx.x * 256 + threadIdx.x;
    const int b = n >> 14, thw = n & 16383;
    sxq[n] = np_sumsq_256(x + (long)b * 4194304 + thw, 16384);
}

__global__ __launch_bounds__(256) void vq_swq(const float* __restrict__ w,
                                              float* __restrict__ swq) {
    const int k = blockIdx.x * 256 + threadIdx.x;
    swq[k] = np_sumsq_256(w + (long)k * 256, 1);
}

// ---- W transpose Wt[c][k] (used by resolve v2 and the R3 fallback) ----
__global__ __launch_bounds__(64) void vq_wt(const float* __restrict__ w,
                                            float* __restrict__ wt) {
    const int k = blockIdx.x;
    const int lane = threadIdx.x;
    const float4 v = reinterpret_cast<const float4*>(w + (size_t)k * 256)[lane];
    wt[(size_t)(4 * lane + 0) * 1024 + k] = v.x;
    wt[(size_t)(4 * lane + 1) * 1024 + k] = v.y;
    wt[(size_t)(4 * lane + 2) * 1024 + k] = v.z;
    wt[(size_t)(4 * lane + 3) * 1024 + k] = v.w;
}

// ---- split weight into bf16 hi/lo planes ----
__global__ __launch_bounds__(256) void vq_split_w(const float* __restrict__ w,
                                                  unsigned short* __restrict__ wh,
                                                  unsigned short* __restrict__ wl) {
    const int i = blockIdx.x * 256 + threadIdx.x;   // 262144
    const float v = w[i];
    const unsigned short h = bf16_rne(v);
    wh[i] = h;
    wl[i] = bf16_rne(v - bf16_to_f(h));
}

// ---- split + transpose x into bf16 planes xh[n][c], xl[n][c] ----
__global__ __launch_bounds__(256) void vq_split_x(const float* __restrict__ x,
                                                  unsigned short* __restrict__ xh,
                                                  unsigned short* __restrict__ xl) {
    __shared__ float tile[64][65];
    const int bid = blockIdx.x;
    const int b  = bid >> 10;
    const int ct = (bid >> 8) & 3;
    const int tt = bid & 255;
    const float* xb = x + (size_t)b * 4194304 + (size_t)(ct * 64) * 16384 + tt * 64;
    const int tw = threadIdx.x & 63;
    const int cg = threadIdx.x >> 6;   // 0..3
    #pragma unroll
    for (int i = 0; i < 16; i++) {
        const int cc = cg * 16 + i;
        tile[cc][tw] = xb[(size_t)cc * 16384 + tw];
    }
    __syncthreads();
    const int c = threadIdx.x & 63;
    #pragma unroll
    for (int i = 0; i < 16; i++) {
        const int t = cg * 16 + i;
        const float v = tile[c][t];
        const unsigned short h = bf16_rne(v);
        const unsigned short l = bf16_rne(v - bf16_to_f(h));
        const size_t n = (size_t)b * 16384 + tt * 64 + t;
        xh[n * 256 + ct * 64 + c] = h;
        xl[n * 256 + ct * 64 + c] = l;
    }
}

// ---- screen: 3-product bf16 MFMA scores, per-token top-2, flag near-ties ----
__global__ __launch_bounds__(256) void vq_screen(const unsigned short* __restrict__ xh,
                                                 const unsigned short* __restrict__ xl,
                                                 const unsigned short* __restrict__ wh,
                                                 const unsigned short* __restrict__ wl,
                                                 const float* __restrict__ swq,
                                                 int* __restrict__ winner,
                                                 int* __restrict__ flag,
                                                 int* __restrict__ count) {
    __shared__ float sw_s[1024];
    __shared__ float r_m1[4][64];
    __shared__ float r_m2[4][64];
    __shared__ int   r_i1[4][64];
    const int tid = threadIdx.x;
    for (int i = tid; i < 1024; i += 256) sw_s[i] = swq[i];
    __syncthreads();

    const int n0 = blockIdx.x * 64;
    const int wv = tid >> 6, lane = tid & 63;
    const int l15 = lane & 15, lq = lane >> 4;

    const size_t aoff = ((size_t)n0 + l15) * 256 + lq * 8;
    const size_t boff = ((size_t)(wv * 256) + l15) * 256 + lq * 8;

    float m1[16], m2[16];
    int   i1[16];
    #pragma unroll
    for (int r = 0; r < 16; r++) { m1[r] = 1e30f; m2[r] = 1e30f; i1[r] = 0; }

    for (int kt = 0; kt < 16; kt++) {
        f32x4 acc[4];
        #pragma unroll
        for (int mt = 0; mt < 4; mt++) acc[mt] = (f32x4){0.f, 0.f, 0.f, 0.f};
        #pragma unroll
        for (int cs = 0; cs < 8; cs++) {
            const bf16x8 bh = *(const bf16x8*)(wh + boff + (size_t)kt * 4096 + cs * 32);
            const bf16x8 bl = *(const bf16x8*)(wl + boff + (size_t)kt * 4096 + cs * 32);
            #pragma unroll
            for (int mt = 0; mt < 4; mt++) {
                const bf16x8 ah = *(const bf16x8*)(xh + aoff + (size_t)mt * 4096 + cs * 32);
                const bf16x8 al = *(const bf16x8*)(xl + aoff + (size_t)mt * 4096 + cs * 32);
                acc[mt] = __builtin_amdgcn_mfma_f32_16x16x32_bf16(ah, bh, acc[mt], 0, 0, 0);
                acc[mt] = __builtin_amdgcn_mfma_f32_16x16x32_bf16(al, bh, acc[mt], 0, 0, 0);
                acc[mt] = __builtin_amdgcn_mfma_f32_16x16x32_bf16(ah, bl, acc[mt], 0, 0, 0);
            }
        }
        const int k = wv * 256 + kt * 16 + l15;   // C/D col = l15
        const float snk = sw_s[k];
        #pragma unroll
        for (int mt = 0; mt < 4; mt++)
            #pragma unroll
            for (int r = 0; r < 4; r++) {
                const float t = fmaf(-2.f, acc[mt][r], snk);
                const int row = mt * 4 + r;       // token = n0+16mt+4lq+r
                if (t < m1[row]) { m2[row] = m1[row]; m1[row] = t; i1[row] = k; }
                else              m2[row] = fminf(m2[row], t);
            }
    }

    #pragma unroll
    for (int mm = 1; mm < 16; mm <<= 1) {
        #pragma unroll
        for (int row = 0; row < 16; row++) {
            const float om1 = __shfl_xor(m1[row], mm);
            const int   oi1 = __shfl_xor(i1[row], mm);
            const float om2 = __shfl_xor(m2[row], mm);
            if (om1 < m1[row]) { m2[row] = fminf(m1[row], om2); m1[row] = om1; i1[row] = oi1; }
            else               { m2[row] = fminf(m2[row], om1); }
        }
    }
    if (l15 == 0) {
        #pragma unroll
        for (int mt = 0; mt < 4; mt++)
            #pragma unroll
            for (int r = 0; r < 4; r++) {
                const int tok = mt * 16 + lq * 4 + r;
                r_m1[wv][tok] = m1[mt * 4 + r];
                r_m2[wv][tok] = m2[mt * 4 + r];
                r_i1[wv][tok] = i1[mt * 4 + r];
            }
    }
    __syncthreads();
    if (tid < 64) {
        float b1 = r_m1[0][tid], b2 = r_m2[0][tid];
        int   bi = r_i1[0][tid];
        #pragma unroll
        for (int w2 = 1; w2 < 4; w2++) {
            const float o1 = r_m1[w2][tid], o2 = r_m2[w2][tid];
            const int   oi = r_i1[w2][tid];
            if (o1 < b1) { b2 = fminf(b1, o2); b1 = o1; bi = oi; }
            else           b2 = fminf(b2, o1);
        }
        const int n = n0 + tid;
        if (b2 - b1 > MARGIN) {
            winner[n] = bi;
        } else {
            winner[n] = -1;
            const int p = atomicAdd(count, 1);
            flag[p] = n;
        }
    }
}

// ---- resolve v2: np-exact rescore of flagged tokens, coalesced wt loads ----
// Block iteration = 4 tokens. Thread tid covers codes k = tid + 256q, q=0..3,
// as 16 independent sequential fma chains (ascending c == np sgemm order).
__global__ __launch_bounds__(256) void vq_resolve2(const float* __restrict__ x,
                                                   const float* __restrict__ wt,
                                                   const float* __restrict__ sxq,
                                                   const float* __restrict__ swq,
                                                   const int* __restrict__ flag,
                                                   const int* __restrict__ count,
                                                   int* __restrict__ winner) {
    __shared__ float xsh[4][256];
    __shared__ int   toks[4];
    __shared__ float r_d[4][4];
    __shared__ int   r_k[4][4];

    const int cnt = *count;
    const int tid = threadIdx.x;
    const int groups = (cnt + 3) >> 2;

    for (int g = blockIdx.x; g < groups; g += gridDim.x) {
        if (tid < 4) toks[tid] = (4 * g + tid < cnt) ? flag[4 * g + tid] : -1;
        __syncthreads();
        #pragma unroll
        for (int i = 0; i < 4; i++) {
            const int n = toks[i];
            float v = 0.f;
            if (n >= 0) {
                const int b = n >> 14, thw = n & 16383;
                v = x[(size_t)b * 4194304 + (size_t)tid * 16384 + thw];
            }
            xsh[i][tid] = v;
        }
        __syncthreads();

        float acc[4][4];   // [q][token]
        #pragma unroll
        for (int q = 0; q < 4; q++)
            #pragma unroll
            for (int i = 0; i < 4; i++) acc[q][i] = 0.f;

        const float* wp = wt + tid;
        #pragma unroll 4
        for (int c = 0; c < 256; c++) {
            const float w0 = wp[(size_t)c * 1024 + 0];
            const float w1 = wp[(size_t)c * 1024 + 256];
            const float w2 = wp[(size_t)c * 1024 + 512];
            const float w3 = wp[(size_t)c * 1024 + 768];
            #pragma unroll
            for (int i = 0; i < 4; i++) {
                const float xc = xsh[i][c];
                acc[0][i] = fmaf(xc, w0, acc[0][i]);
                acc[1][i] = fmaf(xc, w1, acc[1][i]);
                acc[2][i] = fmaf(xc, w2, acc[2][i]);
                acc[3][i] = fmaf(xc, w3, acc[3][i]);
            }
        }

        // np distances + lexicographic (d,k) argmin per token
        const float swk[4] = {swq[tid], swq[tid + 256], swq[tid + 512], swq[tid + 768]};
        #pragma unroll
        for (int i = 0; i < 4; i++) {
            const int n = toks[i];
            float bd = 1e30f;
            int   bk = 0x7fffffff;
            if (n >= 0) {
                const float sx = sxq[n];
                #pragma unroll
                for (int q = 0; q < 4; q++) {
                    const int k = tid + 256 * q;
                    const float s1 = sx + swk[q];
                    const float d  = fmaf(-2.f, acc[q][i], s1);
                    if (d < bd || (d == bd && k < bk)) { bd = d; bk = k; }
                }
            }
            // wave lexicographic reduce
            #pragma unroll
            for (int mm = 1; mm < 64; mm <<= 1) {
                const float od = __shfl_xor(bd, mm);
                const int   ok = __shfl_xor(bk, mm);
                if (od < bd || (od == bd && ok < bk)) { bd = od; bk = ok; }
            }
            if ((tid & 63) == 0) { r_d[tid >> 6][i] = bd; r_k[tid >> 6][i] = bk; }
        }
        __syncthreads();
        if (tid < 4) {
            const int n = toks[tid];
            if (n >= 0) {
                float bd = r_d[0][tid]; int bk = r_k[0][tid];
                #pragma unroll
                for (int wv = 1; wv < 4; wv++) {
                    const float od = r_d[wv][tid];
                    const int   ok = r_k[wv][tid];
                    if (od < bd || (od == bd && ok < bk)) { bd = od; bk = ok; }
                }
                winner[n] = bk;
            }
        }
        __syncthreads();
    }
}

// ---- gather ----
__global__ __launch_bounds__(256) void vq_gather(const float* __restrict__ w,
                                                 const int* __restrict__ winner,
                                                 float* __restrict__ out) {
    const size_t idx = (size_t)blockIdx.x * 256 + threadIdx.x;
    const int n = (int)(idx >> 6);
    const int c4 = (int)(idx & 63);
    reinterpret_cast<float4*>(out)[idx] =
        reinterpret_cast<const float4*>(w + (size_t)winner[n] * 256)[c4];
}

// ================= R3 fallback (proven-correct) =================
#define TPB 32
__global__ __launch_bounds__(256) void vq_main(const float* __restrict__ x,
                                               const float* __restrict__ sxq,
                                               const float* __restrict__ swq,
                                               const float* __restrict__ wt,
                                               const float* __restrict__ weight,
                                               float* __restrict__ out) {
    __shared__ __align__(16) float xs[256 * TPB];
    __shared__ float wn[1024];
    __shared__ float sxs[TPB];
    __shared__ float red_s[4][TPB];
    __shared__ int   red_i[4][TPB];
    __shared__ int   fidx[TPB];

    const int tid = threadIdx.x;
    const int n0 = blockIdx.x * TPB;
    const int b = n0 >> 14, thw = n0 & 16383;
    const float* xb = x + (size_t)b * 4194304 + thw;

    for (int i = tid; i < 256 * TPB; i += 256) {
        int t = i & (TPB - 1);
        int c = i >> 5;
        xs[c * TPB + t] = xb[(size_t)c * 16384 + t];
    }
    for (int i = tid; i < 1024; i += 256) wn[i] = swq[i];
    if (tid < TPB) sxs[tid] = sxq[n0 + tid];
    __syncthreads();

    const int lane = tid & 63, wv = tid >> 6;
    const int tg = lane & 7, cg = lane >> 3;
    float sxr[4];
    #pragma unroll
    for (int j = 0; j < 4; j++) sxr[j] = sxs[4 * tg + j];
    float bestS[4]; int bestI[4];
    #pragma unroll
    for (int j = 0; j < 4; j++) { bestS[j] = 1e30f; bestI[j] = 0x7fffffff; }

    for (int kb = 0; kb < 1024; kb += 256) {
        const int kbase = kb + 64 * wv + 8 * cg;
        float acc[4][8];
        #pragma unroll
        for (int j = 0; j < 4; j++)
            #pragma unroll
            for (int q = 0; q < 8; q++) acc[j][q] = 0.f;
        const float* wtp = wt + kbase;
        #pragma unroll 4
        for (int c = 0; c < 256; c++) {
            const float4 xv = *reinterpret_cast<const float4*>(&xs[c * TPB + 4 * tg]);
            const float4 w0 = *reinterpret_cast<const float4*>(wtp + (size_t)c * 1024);
            const float4 w1 = *reinterpret_cast<const float4*>(wtp + (size_t)c * 1024 + 4);
            const float xr[4] = {xv.x, xv.y, xv.z, xv.w};
            const float wr[8] = {w0.x, w0.y, w0.z, w0.w, w1.x, w1.y, w1.z, w1.w};
            #pragma unroll
            for (int j = 0; j < 4; j++)
                #pragma unroll
                for (int q = 0; q < 8; q++)
                    acc[j][q] = fmaf(xr[j], wr[q], acc[j][q]);
        }
        #pragma unroll
        for (int q = 0; q < 8; q++) {
            const int k = kbase + q;
            const float wnk = wn[k];
            #pragma unroll
            for (int j = 0; j < 4; j++) {
                const float s1 = sxr[j] + wnk;
                const float d = fmaf(-2.f, acc[j][q], s1);
                if (d < bestS[j]) { bestS[j] = d; bestI[j] = k; }
            }
        }
    }
    #pragma unroll
    for (int m = 8; m < 64; m <<= 1) {
        #pragma unroll
        for (int j = 0; j < 4; j++) {
            const float os = __shfl_xor(bestS[j], m);
            const int   oi = __shfl_xor(bestI[j], m);
            if (os < bestS[j] || (os == bestS[j] && oi < bestI[j])) {
                bestS[j] = os; bestI[j] = oi;
            }
        }
    }
    if (cg == 0) {
        #pragma unroll
        for (int j = 0; j < 4; j++) {
            red_s[wv][4 * tg + j] = bestS[j];
            red_i[wv][4 * tg + j] = bestI[j];
        }
    }
    __syncthreads();
    if (tid < TPB) {
        float bs = red_s[0][tid]; int bi = red_i[0][tid];
        #pragma unroll
        for (int w2 = 1; w2 < 4; w2++) {
            const float s2 = red_s[w2][tid];
            const int   i2 = red_i[w2][tid];
            if (s2 < bs || (s2 == bs && i2 < bi)) { bs = s2; bi = i2; }
        }
        fidx[tid] = bi;
    }
    __syncthreads();
    for (int i = tid; i < TPB * 256; i += 256) {
        const int t = i >> 8, c = i & 255;
        out[(size_t)(n0 + t) * 256 + c] = weight[(size_t)fidx[t] * 256 + c];
    }
}

// ================= launch =================
extern "C" void kernel_launch(void* const* d_in, const int* in_sizes, int n_in,
                              void* d_out, int out_size, void* d_ws, size_t ws_size,
                              hipStream_t stream) {
    const float* x = (const float*)d_in[0];
    const float* w = (const float*)d_in[1];
    float* out = (float*)d_out;

    char* p = (char*)d_ws;
    int*   count  = (int*)p;                         p += 256;
    int*   winner = (int*)p;                         p += 65536 * 4;
    int*   flag   = (int*)p;                         p += 65536 * 4;
    float* sxq    = (float*)p;                       p += 65536 * 4;
    float* swq    = (float*)p;                       p += 1024 * 4;
    float* wt     = (float*)p;                       p += 262144 * 4;
    unsigned short* wh = (unsigned short*)p;         p += 262144 * 2;
    unsigned short* wl = (unsigned short*)p;         p += 262144 * 2;
    unsigned short* xh = (unsigned short*)p;         p += 16777216 * 2;
    unsigned short* xl = (unsigned short*)p;         p += 16777216 * 2;
    const size_t need_fast = (size_t)(p - (char*)d_ws);

    if (ws_size >= need_fast) {
        hipMemsetAsync(count, 0, 4, stream);
        vq_sxq<<<256, 256, 0, stream>>>(x, sxq);
        vq_swq<<<4, 256, 0, stream>>>(w, swq);
        vq_wt<<<1024, 64, 0, stream>>>(w, wt);
        vq_split_w<<<1024, 256, 0, stream>>>(w, wh, wl);
        vq_split_x<<<4096, 256, 0, stream>>>(x, xh, xl);
        vq_screen<<<1024, 256, 0, stream>>>(xh, xl, wh, wl, swq, winner, flag, count);
        vq_resolve2<<<1024, 256, 0, stream>>>(x, wt, sxq, swq, flag, count, winner);
        vq_gather<<<16384, 256, 0, stream>>>(w, winner, out);
    } else {
        // proven R3 fallback (needs ~1.3 MB)
        float* sxq2 = (float*)d_ws;
        float* swq2 = sxq2 + 65536;
        float* wt2  = swq2 + 1024;
        vq_sxq<<<256, 256, 0, stream>>>(x, sxq2);
        vq_swq<<<4, 256, 0, stream>>>(w, swq2);
        vq_wt<<<1024, 64, 0, stream>>>(w, wt2);
        vq_main<<<65536 / TPB, 256, 0, stream>>>(x, sxq2, swq2, wt2, w, out);
    }
}